// Round 1
// baseline (2525.977 us; speedup 1.0000x reference)
//
#include <hip/hip_runtime.h>

#define N_VARS 64
#define HID    256
#define HID2   128
#define BATCH  16384
#define TB     64      // batch rows per block
#define NTHR   512     // threads per block

// Fused per-variable MLP step:
//   inp = [Y*mask_i, u_i]  (65)
//   h1 = relu(inp @ W1[i] + b1[i])   (256)
//   h2 = relu(h1  @ W2[i] + b2[i])   (128)
//   y  = h2 @ W3[i] + b3[i]
//   Y[:, i] = y
__global__ __launch_bounds__(NTHR, 1)
void sen_step(const float* __restrict__ U,
              const int*   __restrict__ G,
              const float* __restrict__ W1,
              const float* __restrict__ b1,
              const float* __restrict__ W2,
              const float* __restrict__ b2,
              const float* __restrict__ W3,
              const float* __restrict__ b3,
              float* __restrict__ Y,
              int i)
{
    __shared__ float m_lds[N_VARS];
    __shared__ float inp[TB * 66];    // [64][66]: cols 0..63 masked Y, col 64 = u
    __shared__ float h1s[TB * 258];   // [64][258] padded
    __shared__ float h2s[TB * 130];   // [64][130] padded

    const int tid  = threadIdx.x;
    const int row0 = blockIdx.x * TB;

    // --- mask row i: m[j] = (G[j][i] > 0) ---
    if (tid < N_VARS) m_lds[tid] = (G[tid * N_VARS + i] > 0) ? 1.0f : 0.0f;
    __syncthreads();

    // --- stage masked input tile (coalesced Y reads) ---
    for (int idx = tid; idx < TB * N_VARS; idx += NTHR) {
        const int r = idx >> 6, j = idx & 63;
        inp[r * 66 + j] = Y[(size_t)(row0 + r) * N_VARS + j] * m_lds[j];
    }
    if (tid < TB) inp[tid * 66 + 64] = U[(size_t)(row0 + tid) * N_VARS + i];
    __syncthreads();

    // ================= Layer 1: [64 x 65] @ [65 x 256] =================
    {
        const int ct = tid & 31;   // 32 col groups * 8 cols = 256
        const int rt = tid >> 5;   // 16 row groups * 4 rows = 64
        float acc[4][8];
        const float* b1p = b1 + i * HID + ct * 8;
        #pragma unroll
        for (int c = 0; c < 8; ++c) {
            const float bv = b1p[c];
            #pragma unroll
            for (int r = 0; r < 4; ++r) acc[r][c] = bv;
        }
        const float* W1p = W1 + (size_t)i * 65 * HID;
        for (int k = 0; k < 65; ++k) {
            const float4 wlo = *(const float4*)(W1p + k * HID + ct * 8);
            const float4 whi = *(const float4*)(W1p + k * HID + ct * 8 + 4);
            #pragma unroll
            for (int r = 0; r < 4; ++r) {
                const float x = inp[(rt * 4 + r) * 66 + k];
                acc[r][0] = fmaf(x, wlo.x, acc[r][0]);
                acc[r][1] = fmaf(x, wlo.y, acc[r][1]);
                acc[r][2] = fmaf(x, wlo.z, acc[r][2]);
                acc[r][3] = fmaf(x, wlo.w, acc[r][3]);
                acc[r][4] = fmaf(x, whi.x, acc[r][4]);
                acc[r][5] = fmaf(x, whi.y, acc[r][5]);
                acc[r][6] = fmaf(x, whi.z, acc[r][6]);
                acc[r][7] = fmaf(x, whi.w, acc[r][7]);
            }
        }
        #pragma unroll
        for (int r = 0; r < 4; ++r)
            #pragma unroll
            for (int c = 0; c < 8; ++c)
                h1s[(rt * 4 + r) * 258 + ct * 8 + c] = fmaxf(acc[r][c], 0.0f);
    }
    __syncthreads();

    // ================= Layer 2: [64 x 256] @ [256 x 128] =================
    {
        const int ct = tid & 15;   // 16 col groups * 8 cols = 128
        const int rt = tid >> 4;   // 32 row groups * 2 rows = 64
        float acc[2][8];
        const float* b2p = b2 + i * HID2 + ct * 8;
        #pragma unroll
        for (int c = 0; c < 8; ++c) {
            const float bv = b2p[c];
            acc[0][c] = bv; acc[1][c] = bv;
        }
        const float* W2p = W2 + (size_t)i * HID * HID2;
        for (int k = 0; k < HID; ++k) {
            const float4 wlo = *(const float4*)(W2p + k * HID2 + ct * 8);
            const float4 whi = *(const float4*)(W2p + k * HID2 + ct * 8 + 4);
            #pragma unroll
            for (int r = 0; r < 2; ++r) {
                const float x = h1s[(rt * 2 + r) * 258 + k];
                acc[r][0] = fmaf(x, wlo.x, acc[r][0]);
                acc[r][1] = fmaf(x, wlo.y, acc[r][1]);
                acc[r][2] = fmaf(x, wlo.z, acc[r][2]);
                acc[r][3] = fmaf(x, wlo.w, acc[r][3]);
                acc[r][4] = fmaf(x, whi.x, acc[r][4]);
                acc[r][5] = fmaf(x, whi.y, acc[r][5]);
                acc[r][6] = fmaf(x, whi.z, acc[r][6]);
                acc[r][7] = fmaf(x, whi.w, acc[r][7]);
            }
        }
        #pragma unroll
        for (int r = 0; r < 2; ++r)
            #pragma unroll
            for (int c = 0; c < 8; ++c)
                h2s[(rt * 2 + r) * 130 + ct * 8 + c] = fmaxf(acc[r][c], 0.0f);
    }
    __syncthreads();

    // ================= Layer 3: [64 x 128] @ [128 x 1] =================
    {
        const int r = tid >> 3;    // 64 rows
        const int q = tid & 7;     // 8 partial sums per row
        const float* W3p = W3 + (size_t)i * HID2;
        float a = 0.0f;
        #pragma unroll
        for (int kk = 0; kk < 16; ++kk) {
            const int k = q * 16 + kk;
            a = fmaf(h2s[r * 130 + k], W3p[k], a);
        }
        a += __shfl_xor(a, 1);
        a += __shfl_xor(a, 2);
        a += __shfl_xor(a, 4);
        if (q == 0) Y[(size_t)(row0 + r) * N_VARS + i] = a + b3[i];
    }
}

extern "C" void kernel_launch(void* const* d_in, const int* in_sizes, int n_in,
                              void* d_out, int out_size, void* d_ws, size_t ws_size,
                              hipStream_t stream) {
    // inputs: X, U, causal_graph, W1, b1, W2, b2, W3, b3
    const float* U  = (const float*)d_in[1];
    const int*   G  = (const int*)  d_in[2];
    const float* W1 = (const float*)d_in[3];
    const float* b1 = (const float*)d_in[4];
    const float* W2 = (const float*)d_in[5];
    const float* b2 = (const float*)d_in[6];
    const float* W3 = (const float*)d_in[7];
    const float* b3 = (const float*)d_in[8];
    float* Y = (float*)d_out;

    // X is never actually read by the recursion: parents of variable i are
    // strictly j < i (upper-triangular graph), and those Y columns are
    // computed by earlier steps; all other columns are masked to zero.
    for (int i = 0; i < N_VARS; ++i) {
        sen_step<<<BATCH / TB, NTHR, 0, stream>>>(U, G, W1, b1, W2, b2, W3, b3, Y, i);
    }
}

// Round 2
// 705.688 us; speedup vs baseline: 3.5795x; 3.5795x over previous
//
#include <hip/hip_runtime.h>

#define N_VARS 64
#define HID    256
#define HID2   128
#define BATCH  16384

typedef unsigned short u16;
typedef __attribute__((ext_vector_type(8))) short short8;
typedef __attribute__((ext_vector_type(4))) float f32x4;

// ---------- bf16 split helpers ----------
__device__ __forceinline__ u16 f2bf(float x) {
    union { float f; unsigned int u; } a; a.f = x;
    unsigned int r = a.u + 0x7fffu + ((a.u >> 16) & 1u);   // RTN-even
    return (u16)(r >> 16);
}
__device__ __forceinline__ float bf2f(u16 h) {
    union { unsigned int u; float f; } a; a.u = ((unsigned int)h) << 16;
    return a.f;
}

// ================= weight pre-pack kernels =================
// Pack W[k][n] into P[kg][n][kw] (kg=k>>3, kw=k&7) so an MFMA B-fragment
// (8 consecutive k at fixed n) is one contiguous 16B load:
//   lane l of ktile kt loads P[(kt*4 + (l>>4))*N + n0 + (l&15)][0..7].
__global__ void prep_w1(const float* __restrict__ W1, u16* __restrict__ Ph,
                        u16* __restrict__ Pl) {
    int idx = blockIdx.x * 256 + threadIdx.x;       // 64*96*256
    if (idx >= 64 * 96 * 256) return;
    int n = idx & 255;
    int k = (idx >> 8) % 96;
    int v = idx / (96 * 256);
    float w = (k < 65) ? W1[((size_t)v * 65 + k) * 256 + n] : 0.0f;
    u16 h = f2bf(w);
    u16 l = f2bf(w - bf2f(h));
    size_t o = (((size_t)(v * 12 + (k >> 3)) * 256 + n) << 3) + (k & 7);
    Ph[o] = h; Pl[o] = l;
}
__global__ void prep_w2(const float* __restrict__ W2, u16* __restrict__ Ph,
                        u16* __restrict__ Pl) {
    int idx = blockIdx.x * 256 + threadIdx.x;       // 64*256*128
    if (idx >= 64 * 256 * 128) return;
    int n = idx & 127;
    int k = (idx >> 7) & 255;
    int v = idx >> 15;
    float w = W2[((size_t)v * 256 + k) * 128 + n];
    u16 h = f2bf(w);
    u16 l = f2bf(w - bf2f(h));
    size_t o = (((size_t)(v * 32 + (k >> 3)) * 128 + n) << 3) + (k & 7);
    Ph[o] = h; Pl[o] = l;
}

// ================= fused MFMA step kernel =================
#define RT    64            // batch rows per block
#define AST   104           // A LDS stride (elems): 96 padded, 208 B (16B-mult)
#define H1ST  264           // h1 LDS stride: 256 padded, 528 B (16B-mult)

__global__ __launch_bounds__(512, 1)
void sen_step_mfma(const float* __restrict__ U, const int* __restrict__ G,
                   const u16* __restrict__ P1h, const u16* __restrict__ P1l,
                   const u16* __restrict__ P2h, const u16* __restrict__ P2l,
                   const float* __restrict__ b1, const float* __restrict__ b2,
                   const float* __restrict__ W3, const float* __restrict__ b3,
                   float* __restrict__ Y, int v)
{
    __shared__ __attribute__((aligned(16))) u16 Ah[RT * AST];
    __shared__ __attribute__((aligned(16))) u16 Al[RT * AST];
    __shared__ __attribute__((aligned(16))) u16 h1h[RT * H1ST];
    __shared__ __attribute__((aligned(16))) u16 h1l[RT * H1ST];
    __shared__ float m_lds[64];
    __shared__ float yp[4][64];

    const int tid  = threadIdx.x;
    const int row0 = blockIdx.x * RT;

    if (tid < 64) m_lds[tid] = (G[tid * 64 + v] > 0) ? 1.0f : 0.0f;
    __syncthreads();

    // ---- stage A = [Y*mask | u | 0-pad] as bf16 hi/lo ----
    {
        const int row = tid >> 3, cs = (tid & 7) * 8;
        const float4* y4 = (const float4*)(Y + (size_t)(row0 + row) * 64 + cs);
        float4 a = y4[0], b = y4[1];
        float xv[8] = {a.x, a.y, a.z, a.w, b.x, b.y, b.z, b.w};
        short8 vh, vl;
        #pragma unroll
        for (int j = 0; j < 8; ++j) {
            float x = xv[j] * m_lds[cs + j];
            u16 h = f2bf(x);
            vh[j] = (short)h;
            vl[j] = (short)f2bf(x - bf2f(h));
        }
        *(short8*)&Ah[row * AST + cs] = vh;
        *(short8*)&Al[row * AST + cs] = vl;
        if ((tid & 7) == 0) {   // u at k=64, zeros k=65..95
            float u = U[(size_t)(row0 + row) * 64 + v];
            u16 uh = f2bf(u), ul = f2bf(u - bf2f(uh));
            short8 z = {0,0,0,0,0,0,0,0};
            short8 zh = z, zl = z;
            zh[0] = (short)uh; zl[0] = (short)ul;
            *(short8*)&Ah[row * AST + 64] = zh;
            *(short8*)&Al[row * AST + 64] = zl;
            *(short8*)&Ah[row * AST + 72] = z;
            *(short8*)&Al[row * AST + 72] = z;
            *(short8*)&Ah[row * AST + 80] = z;
            *(short8*)&Al[row * AST + 80] = z;
            *(short8*)&Ah[row * AST + 88] = z;
            *(short8*)&Al[row * AST + 88] = z;
        }
    }
    __syncthreads();

    const int w  = tid >> 6, l = tid & 63;
    const int rh = w >> 2, cg = w & 3;       // row-half, col-group
    const int lr = l & 15, lk = l >> 4;      // lane row/col-in-frag, k-group

    // ================= Layer 1: C[64][256], K=96 =================
    {
        f32x4 acc[2][4];
        #pragma unroll
        for (int ni = 0; ni < 4; ++ni) {
            float bv = b1[v * 256 + cg * 64 + ni * 16 + lr];
            #pragma unroll
            for (int mi = 0; mi < 2; ++mi)
                acc[mi][ni] = (f32x4){bv, bv, bv, bv};
        }
        #pragma unroll
        for (int kt = 0; kt < 3; ++kt) {
            short8 Afh[2], Afl[2];
            #pragma unroll
            for (int mi = 0; mi < 2; ++mi) {
                const int row = rh * 32 + mi * 16 + lr;
                const int kb  = kt * 32 + lk * 8;
                Afh[mi] = *(const short8*)&Ah[row * AST + kb];
                Afl[mi] = *(const short8*)&Al[row * AST + kb];
            }
            #pragma unroll
            for (int ni = 0; ni < 4; ++ni) {
                const int col = cg * 64 + ni * 16 + lr;
                const size_t off = (((size_t)(v * 12 + kt * 4 + lk) * 256 + col) << 3);
                short8 Bh = *(const short8*)&P1h[off];
                short8 Bl = *(const short8*)&P1l[off];
                #pragma unroll
                for (int mi = 0; mi < 2; ++mi) {
                    acc[mi][ni] = __builtin_amdgcn_mfma_f32_16x16x32_bf16(Afh[mi], Bh, acc[mi][ni], 0, 0, 0);
                    acc[mi][ni] = __builtin_amdgcn_mfma_f32_16x16x32_bf16(Afh[mi], Bl, acc[mi][ni], 0, 0, 0);
                    acc[mi][ni] = __builtin_amdgcn_mfma_f32_16x16x32_bf16(Afl[mi], Bh, acc[mi][ni], 0, 0, 0);
                }
            }
        }
        // relu + split + store h1
        #pragma unroll
        for (int mi = 0; mi < 2; ++mi)
            #pragma unroll
            for (int ni = 0; ni < 4; ++ni)
                #pragma unroll
                for (int r = 0; r < 4; ++r) {
                    float x = fmaxf(acc[mi][ni][r], 0.0f);
                    const int row = rh * 32 + mi * 16 + lk * 4 + r;
                    const int col = cg * 64 + ni * 16 + lr;
                    u16 h = f2bf(x);
                    h1h[row * H1ST + col] = h;
                    h1l[row * H1ST + col] = f2bf(x - bf2f(h));
                }
    }
    __syncthreads();

    // ================= Layer 2: C[64][128], K=256  (+ fused layer 3) =================
    {
        f32x4 acc[2][2];
        #pragma unroll
        for (int ni = 0; ni < 2; ++ni) {
            float bv = b2[v * 128 + cg * 32 + ni * 16 + lr];
            #pragma unroll
            for (int mi = 0; mi < 2; ++mi)
                acc[mi][ni] = (f32x4){bv, bv, bv, bv};
        }
        #pragma unroll
        for (int kt = 0; kt < 8; ++kt) {
            short8 Afh[2], Afl[2];
            #pragma unroll
            for (int mi = 0; mi < 2; ++mi) {
                const int row = rh * 32 + mi * 16 + lr;
                const int kb  = kt * 32 + lk * 8;
                Afh[mi] = *(const short8*)&h1h[row * H1ST + kb];
                Afl[mi] = *(const short8*)&h1l[row * H1ST + kb];
            }
            #pragma unroll
            for (int ni = 0; ni < 2; ++ni) {
                const int col = cg * 32 + ni * 16 + lr;
                const size_t off = (((size_t)(v * 32 + kt * 4 + lk) * 128 + col) << 3);
                short8 Bh = *(const short8*)&P2h[off];
                short8 Bl = *(const short8*)&P2l[off];
                #pragma unroll
                for (int mi = 0; mi < 2; ++mi) {
                    acc[mi][ni] = __builtin_amdgcn_mfma_f32_16x16x32_bf16(Afh[mi], Bh, acc[mi][ni], 0, 0, 0);
                    acc[mi][ni] = __builtin_amdgcn_mfma_f32_16x16x32_bf16(Afh[mi], Bl, acc[mi][ni], 0, 0, 0);
                    acc[mi][ni] = __builtin_amdgcn_mfma_f32_16x16x32_bf16(Afl[mi], Bh, acc[mi][ni], 0, 0, 0);
                }
            }
        }
        // ---- layer 3 in-register: y += relu(h2)·W3 ----
        float w3c[2];
        #pragma unroll
        for (int ni = 0; ni < 2; ++ni)
            w3c[ni] = W3[v * 128 + cg * 32 + ni * 16 + lr];
        #pragma unroll
        for (int mi = 0; mi < 2; ++mi)
            #pragma unroll
            for (int r = 0; r < 4; ++r) {
                float s = fmaxf(acc[mi][0][r], 0.0f) * w3c[0]
                        + fmaxf(acc[mi][1][r], 0.0f) * w3c[1];
                s += __shfl_xor(s, 1);
                s += __shfl_xor(s, 2);
                s += __shfl_xor(s, 4);
                s += __shfl_xor(s, 8);
                if (lr == 0) yp[cg][rh * 32 + mi * 16 + lk * 4 + r] = s;
            }
    }
    __syncthreads();

    if (tid < 64) {
        float y = yp[0][tid] + yp[1][tid] + yp[2][tid] + yp[3][tid] + b3[v];
        Y[(size_t)(row0 + tid) * 64 + v] = y;
    }
}

// ================= fp32 fallback (R1 kernel) — used only if ws too small =================
#define TB 64
#define NTHR 512
__global__ __launch_bounds__(NTHR, 1)
void sen_step(const float* __restrict__ U, const int* __restrict__ G,
              const float* __restrict__ W1, const float* __restrict__ b1,
              const float* __restrict__ W2, const float* __restrict__ b2,
              const float* __restrict__ W3, const float* __restrict__ b3,
              float* __restrict__ Y, int i)
{
    __shared__ float m_lds[N_VARS];
    __shared__ float inp[TB * 66];
    __shared__ float h1s[TB * 258];
    __shared__ float h2s[TB * 130];
    const int tid = threadIdx.x;
    const int row0 = blockIdx.x * TB;
    if (tid < N_VARS) m_lds[tid] = (G[tid * N_VARS + i] > 0) ? 1.0f : 0.0f;
    __syncthreads();
    for (int idx = tid; idx < TB * N_VARS; idx += NTHR) {
        const int r = idx >> 6, j = idx & 63;
        inp[r * 66 + j] = Y[(size_t)(row0 + r) * N_VARS + j] * m_lds[j];
    }
    if (tid < TB) inp[tid * 66 + 64] = U[(size_t)(row0 + tid) * N_VARS + i];
    __syncthreads();
    {
        const int ct = tid & 31, rt = tid >> 5;
        float acc[4][8];
        const float* b1p = b1 + i * HID + ct * 8;
        #pragma unroll
        for (int c = 0; c < 8; ++c) { const float bv = b1p[c];
            #pragma unroll
            for (int r = 0; r < 4; ++r) acc[r][c] = bv; }
        const float* W1p = W1 + (size_t)i * 65 * HID;
        for (int k = 0; k < 65; ++k) {
            const float4 wlo = *(const float4*)(W1p + k * HID + ct * 8);
            const float4 whi = *(const float4*)(W1p + k * HID + ct * 8 + 4);
            #pragma unroll
            for (int r = 0; r < 4; ++r) {
                const float x = inp[(rt * 4 + r) * 66 + k];
                acc[r][0] = fmaf(x, wlo.x, acc[r][0]); acc[r][1] = fmaf(x, wlo.y, acc[r][1]);
                acc[r][2] = fmaf(x, wlo.z, acc[r][2]); acc[r][3] = fmaf(x, wlo.w, acc[r][3]);
                acc[r][4] = fmaf(x, whi.x, acc[r][4]); acc[r][5] = fmaf(x, whi.y, acc[r][5]);
                acc[r][6] = fmaf(x, whi.z, acc[r][6]); acc[r][7] = fmaf(x, whi.w, acc[r][7]);
            }
        }
        #pragma unroll
        for (int r = 0; r < 4; ++r)
            #pragma unroll
            for (int c = 0; c < 8; ++c)
                h1s[(rt * 4 + r) * 258 + ct * 8 + c] = fmaxf(acc[r][c], 0.0f);
    }
    __syncthreads();
    {
        const int ct = tid & 15, rt = tid >> 4;
        float acc[2][8];
        const float* b2p = b2 + i * HID2 + ct * 8;
        #pragma unroll
        for (int c = 0; c < 8; ++c) { const float bv = b2p[c]; acc[0][c] = bv; acc[1][c] = bv; }
        const float* W2p = W2 + (size_t)i * HID * HID2;
        for (int k = 0; k < HID; ++k) {
            const float4 wlo = *(const float4*)(W2p + k * HID2 + ct * 8);
            const float4 whi = *(const float4*)(W2p + k * HID2 + ct * 8 + 4);
            #pragma unroll
            for (int r = 0; r < 2; ++r) {
                const float x = h1s[(rt * 2 + r) * 258 + k];
                acc[r][0] = fmaf(x, wlo.x, acc[r][0]); acc[r][1] = fmaf(x, wlo.y, acc[r][1]);
                acc[r][2] = fmaf(x, wlo.z, acc[r][2]); acc[r][3] = fmaf(x, wlo.w, acc[r][3]);
                acc[r][4] = fmaf(x, whi.x, acc[r][4]); acc[r][5] = fmaf(x, whi.y, acc[r][5]);
                acc[r][6] = fmaf(x, whi.z, acc[r][6]); acc[r][7] = fmaf(x, whi.w, acc[r][7]);
            }
        }
        #pragma unroll
        for (int r = 0; r < 2; ++r)
            #pragma unroll
            for (int c = 0; c < 8; ++c)
                h2s[(rt * 2 + r) * 130 + ct * 8 + c] = fmaxf(acc[r][c], 0.0f);
    }
    __syncthreads();
    {
        const int r = tid >> 3, q = tid & 7;
        const float* W3p = W3 + (size_t)i * HID2;
        float a = 0.0f;
        #pragma unroll
        for (int kk = 0; kk < 16; ++kk) {
            const int k = q * 16 + kk;
            a = fmaf(h2s[r * 130 + k], W3p[k], a);
        }
        a += __shfl_xor(a, 1); a += __shfl_xor(a, 2); a += __shfl_xor(a, 4);
        if (q == 0) Y[(size_t)(row0 + r) * N_VARS + i] = a + b3[i];
    }
}

extern "C" void kernel_launch(void* const* d_in, const int* in_sizes, int n_in,
                              void* d_out, int out_size, void* d_ws, size_t ws_size,
                              hipStream_t stream) {
    // inputs: X, U, causal_graph, W1, b1, W2, b2, W3, b3  (X never feeds the recursion)
    const float* U  = (const float*)d_in[1];
    const int*   G  = (const int*)  d_in[2];
    const float* W1 = (const float*)d_in[3];
    const float* b1 = (const float*)d_in[4];
    const float* W2 = (const float*)d_in[5];
    const float* b2 = (const float*)d_in[6];
    const float* W3 = (const float*)d_in[7];
    const float* b3 = (const float*)d_in[8];
    float* Y = (float*)d_out;

    const size_t S1 = (size_t)64 * 96 * 256;    // ushorts
    const size_t S2 = (size_t)64 * 256 * 128;
    const size_t need = 2 * (S1 + S2) * sizeof(u16);

    if (ws_size >= need) {
        u16* P1h = (u16*)d_ws;
        u16* P1l = P1h + S1;
        u16* P2h = P1l + S1;
        u16* P2l = P2h + S2;
        prep_w1<<<(64 * 96 * 256) / 256, 256, 0, stream>>>(W1, P1h, P1l);
        prep_w2<<<(64 * 256 * 128) / 256, 256, 0, stream>>>(W2, P2h, P2l);
        for (int v = 0; v < N_VARS; ++v)
            sen_step_mfma<<<BATCH / RT, 512, 0, stream>>>(U, G, P1h, P1l, P2h, P2l,
                                                          b1, b2, W3, b3, Y, v);
    } else {
        for (int i = 0; i < N_VARS; ++i)
            sen_step<<<BATCH / TB, NTHR, 0, stream>>>(U, G, W1, b1, W2, b2, W3, b3, Y, i);
    }
}